// Round 1
// baseline (477.796 us; speedup 1.0000x reference)
//
#include <hip/hip_runtime.h>
#include <math.h>

// Problem constants: N=8192 rows, T=1024 trials, K=10 options
#define T_TRIALS 1024
#define KOPT     10
#define RPB      32                    // rows per block
#define BLOCK    (RPB * KOPT)          // 320 threads = 5 waves

// ---- emit-kernel LDS tiling ----
#define TI       8                     // trials per LDS tile (was 16) -> LDS 21.5 KB, 4+ blocks/CU
#define LSTRIDE  84                    // 8*10 + 4 pad floats; 84%32=20 rotates banks per row; 336B row = 16B-aligned
// ---- T-dimension chunking (checkpointed scan) ----
#define CHUNKS   4
#define TPC      (T_TRIALS / CHUNKS)   // 256 trials per chunk
#define PRETILE  16                    // prepass tile (trials)
#define NPRET    (T_TRIALS / PRETILE)  // 64
#define TILES_PER_CHUNK (TPC / PRETILE) // 16

__device__ __forceinline__ float sigmoidf_(float x) { return 1.0f / (1.0f + expf(-x)); }

// One RW update for the option-k chain (branchless; exact f32 reference arithmetic).
#define STEP(ct, rt)                                              \
    {                                                             \
        float pe = ((rt) == (rt)) ? ((rt) - v) : 0.0f;            \
        float lr = (pe >= 0.0f) ? ap : am;                        \
        float vn = fmaf(lr, pe, v);                               \
        v = ((ct) == k) ? vn : v;                                 \
    }

// ---------------------------------------------------------------------------
// Pre-pass: scan all T trials per (row,option) thread, NO emit, no LDS, no
// barriers. Deposits the exact f32 state at chunk boundaries t=256/512/768.
// The recurrence is deterministic f32, so replaying a chunk from the saved
// state is bit-identical to the monolithic scan.
// ---------------------------------------------------------------------------
__global__ __launch_bounds__(BLOCK) void rw_prepass(
    const int* __restrict__ choices, const float* __restrict__ rewards,
    const float* __restrict__ apP, const float* __restrict__ amP,
    const float* __restrict__ ivP, float* __restrict__ ckpt, int N)
{
    const int j = threadIdx.x;
    const int u = j / KOPT;
    const int k = j - u * KOPT;
    int row = blockIdx.x * RPB + u;
    if (row >= N) row = N - 1;            // clamped dup rows write identical values (benign)

    const float ap = sigmoidf_(apP[0]);
    const float am = sigmoidf_(amP[0]);
    float v = 100.0f * tanhf(ivP[0]);

    const int4*   c4 = (const int4*)  (choices + (size_t)row * T_TRIALS);
    const float4* r4 = (const float4*)(rewards + (size_t)row * T_TRIALS);

    // Depth-2 rolling prefetch of 16-trial tiles (keeps ~2 tiles of loads in
    // flight; compute per tile ~300-400 cyc covers most of LLC/HBM latency).
    int4   ca0 = c4[0], ca1 = c4[1], ca2 = c4[2], ca3 = c4[3];
    float4 ra0 = r4[0], ra1 = r4[1], ra2 = r4[2], ra3 = r4[3];
    int4   cb0 = c4[4], cb1 = c4[5], cb2 = c4[6], cb3 = c4[7];
    float4 rb0 = r4[4], rb1 = r4[5], rb2 = r4[6], rb3 = r4[7];

    for (int tile = 0; tile < NPRET; ++tile) {
        int nx = ((tile + 2) & (NPRET - 1)) * 4;   // wraps near the end; unused then
        int4   cc0 = c4[nx], cc1 = c4[nx + 1], cc2 = c4[nx + 2], cc3 = c4[nx + 3];
        float4 rc0 = r4[nx], rc1 = r4[nx + 1], rc2 = r4[nx + 2], rc3 = r4[nx + 3];

        STEP(ca0.x, ra0.x) STEP(ca0.y, ra0.y) STEP(ca0.z, ra0.z) STEP(ca0.w, ra0.w)
        STEP(ca1.x, ra1.x) STEP(ca1.y, ra1.y) STEP(ca1.z, ra1.z) STEP(ca1.w, ra1.w)
        STEP(ca2.x, ra2.x) STEP(ca2.y, ra2.y) STEP(ca2.z, ra2.z) STEP(ca2.w, ra2.w)
        STEP(ca3.x, ra3.x) STEP(ca3.y, ra3.y) STEP(ca3.z, ra3.z) STEP(ca3.w, ra3.w)

        // Checkpoint the state entering chunks 1..CHUNKS-1 (wave-uniform branch).
        if (((tile + 1) & (TILES_PER_CHUNK - 1)) == 0 && (tile + 1) < NPRET) {
            int cidx = ((tile + 1) / TILES_PER_CHUNK) - 1;   // 0..CHUNKS-2
            ckpt[(size_t)cidx * N * KOPT + (size_t)row * KOPT + k] = v;  // fully coalesced
        }

        ca0 = cb0; ca1 = cb1; ca2 = cb2; ca3 = cb3;
        ra0 = rb0; ra1 = rb1; ra2 = rb2; ra3 = rb3;
        cb0 = cc0; cb1 = cc1; cb2 = cc2; cb3 = cc3;
        rb0 = rc0; rb1 = rc1; rb2 = rc2; rb3 = rc3;
    }
}

// ---------------------------------------------------------------------------
// Emit kernel: block = (row-block, chunk). Scans tpc trials starting at
// t0 = chunk*tpc from the checkpointed state, emits pre-update values via
// double-buffered LDS tiles -> coalesced float4 stores.
// __launch_bounds__(320, 6): target <=~84 VGPR so 4 blocks (20 waves) fit/CU.
// ---------------------------------------------------------------------------
__global__ __launch_bounds__(BLOCK, 6) void rw_emit(
    const int* __restrict__ choices, const float* __restrict__ rewards,
    const float* __restrict__ apP, const float* __restrict__ amP,
    const float* __restrict__ ivP, const float* __restrict__ ckpt,
    float* __restrict__ out, int N, int nchunks, int tpc)
{
    __shared__ float lds[2][RPB * LSTRIDE];   // 2 * 32 * 84 * 4 = 21504 B

    const int j = threadIdx.x;
    const int u = j / KOPT;                   // local row 0..31
    const int k = j - u * KOPT;               // option 0..9
    const int rowblk = blockIdx.x / nchunks;
    const int chunk  = blockIdx.x - rowblk * nchunks;
    int row = rowblk * RPB + u;
    if (row >= N) row = N - 1;
    const int t0 = chunk * tpc;

    const float ap = sigmoidf_(apP[0]);
    const float am = sigmoidf_(amP[0]);
    float v = 100.0f * tanhf(ivP[0]);
    if (chunk > 0)
        v = ckpt[(size_t)(chunk - 1) * N * KOPT + (size_t)row * KOPT + k];

    const int4*   c4 = (const int4*)  (choices + (size_t)row * T_TRIALS + t0);
    const float4* r4 = (const float4*)(rewards + (size_t)row * T_TRIALS + t0);

    // Per-thread LDS write bases for the two buffers.
    float* Lw[2] = { &lds[0][u * LSTRIDE + k], &lds[1][u * LSTRIDE + k] };

    // Store-loop assignment: tile = 32 rows x 80 floats = 640 float4 -> 2/thread.
    // idx = w*320 + j -> local row uu = idx/20, vector f4 = idx%20.
    int    s_uu[2], s_f4[2];
    float* s_dst[2];
    bool   s_ok[2];
#pragma unroll
    for (int w = 0; w < 2; ++w) {
        int idx = w * BLOCK + j;
        int uu  = idx / 20;
        int f4  = idx - uu * 20;
        s_uu[w] = uu; s_f4[w] = f4;
        int grow = rowblk * RPB + uu;
        s_ok[w]  = grow < N;
        if (grow >= N) grow = N - 1;
        s_dst[w] = out + (size_t)grow * T_TRIALS * KOPT + (size_t)t0 * KOPT + (size_t)f4 * 4;
    }

    const int ntiles = tpc / TI;

    // Prefetch tile 0 (2 int4 + 2 float4 per 8-trial tile).
    int4   ca0 = c4[0], ca1 = c4[1];
    float4 ra0 = r4[0], ra1 = r4[1];

    for (int tile = 0; tile < ntiles; ++tile) {
        int nx = (tile + 1 < ntiles) ? (tile + 1) * 2 : 0;   // last prefetch unused
        int4   cb0 = c4[nx], cb1 = c4[nx + 1];
        float4 rb0 = r4[nx], rb1 = r4[nx + 1];

        // Emit (pre-update) + update, 8 trials into LDS buffer tile&1.
        float* L = Lw[tile & 1];
        L[0*KOPT] = v; STEP(ca0.x, ra0.x) L[1*KOPT] = v; STEP(ca0.y, ra0.y)
        L[2*KOPT] = v; STEP(ca0.z, ra0.z) L[3*KOPT] = v; STEP(ca0.w, ra0.w)
        L[4*KOPT] = v; STEP(ca1.x, ra1.x) L[5*KOPT] = v; STEP(ca1.y, ra1.y)
        L[6*KOPT] = v; STEP(ca1.z, ra1.z) L[7*KOPT] = v; STEP(ca1.w, ra1.w)

        __syncthreads();   // writes of buf (tile&1) visible; WAR on buffer reuse
                           // is covered one iteration later by the next barrier.

        // Cooperative coalesced store of this tile: 32 rows x 80 floats.
        const float* Ls = &lds[tile & 1][0];
#pragma unroll
        for (int w = 0; w < 2; ++w) {
            float4 val = *(const float4*)(Ls + s_uu[w] * LSTRIDE + s_f4[w] * 4);
            if (s_ok[w]) *(float4*)s_dst[w] = val;
            s_dst[w] += TI * KOPT;          // advance 80 floats to next tile
        }

        ca0 = cb0; ca1 = cb1; ra0 = rb0; ra1 = rb1;
    }
}

extern "C" void kernel_launch(void* const* d_in, const int* in_sizes, int n_in,
                              void* d_out, int out_size, void* d_ws, size_t ws_size,
                              hipStream_t stream)
{
    const int*   choices = (const int*)  d_in[0];
    const float* rewards = (const float*)d_in[1];
    const float* ap      = (const float*)d_in[2];
    const float* am      = (const float*)d_in[3];
    const float* iv      = (const float*)d_in[4];
    float* out = (float*)d_out;

    int N  = in_sizes[0] / T_TRIALS;          // 8192
    int NR = (N + RPB - 1) / RPB;             // 256 row-blocks

    size_t need = (size_t)(CHUNKS - 1) * (size_t)N * KOPT * sizeof(float);  // ~0.98 MB
    if (d_ws != nullptr && ws_size >= need) {
        // Checkpoint pre-pass (no emit), then 4x-parallel emit over T-chunks.
        rw_prepass<<<NR, BLOCK, 0, stream>>>(choices, rewards, ap, am, iv,
                                             (float*)d_ws, N);
        rw_emit<<<NR * CHUNKS, BLOCK, 0, stream>>>(choices, rewards, ap, am, iv,
                                                   (const float*)d_ws, out, N,
                                                   CHUNKS, TPC);
    } else {
        // Fallback: single monolithic scan (chunk 0 covers all of T).
        rw_emit<<<NR, BLOCK, 0, stream>>>(choices, rewards, ap, am, iv, nullptr,
                                          out, N, 1, T_TRIALS);
    }
}

// Round 2
// 447.204 us; speedup vs baseline: 1.0684x; 1.0684x over previous
//
#include <hip/hip_runtime.h>
#include <math.h>

// Problem constants: N=8192 rows, T=1024 trials, K=10 options
#define T_TRIALS 1024
#define KOPT     10
#define KPAD     16                  // lanes per row (option dim padded to 16)
#define RPW      4                   // rows per wave (64/16)
#define WPB      4                   // waves per block
#define RPB      (RPW * WPB)         // 16 rows per block
#define BLOCK    256                 // 4 waves
#define TI       16                  // trials per tile
#define NTILES   (T_TRIALS / TI)     // 64
#define LSTRIDE  172                 // floats/row: 160 data + 12 pad; 688B (16B-aligned); u-stride mod 32 banks => <=2-way (free)
#define BUFSZ    (RPB * LSTRIDE)     // one buffer: 16*172 floats = 11008 B

__device__ __forceinline__ float sigmoidf_(float x) { return 1.0f / (1.0f + expf(-x)); }

// One RW update. Chain shortened to 5 dependent ops: NaN-reward folded into the
// update predicate (bit-exact: ref's NaN path yields chosen + ap*0 == chosen).
#define STEP(ct, rt)                                              \
    {                                                             \
        bool  upd = ((ct) == k) && ((rt) == (rt));                \
        float pe  = (rt) - v;                                     \
        float lr  = (pe >= 0.0f) ? ap : am;                       \
        float vn  = fmaf(lr, pe, v);                              \
        v = upd ? vn : v;                                         \
    }

// Emit 16 pre-update values into per-wave LDS region, updating v after each.
#define EMIT16(L, C0, C1, C2, C3, R0, R1, R2, R3)                         \
    L[ 0*KOPT] = v; STEP(C0.x, R0.x) L[ 1*KOPT] = v; STEP(C0.y, R0.y)     \
    L[ 2*KOPT] = v; STEP(C0.z, R0.z) L[ 3*KOPT] = v; STEP(C0.w, R0.w)     \
    L[ 4*KOPT] = v; STEP(C1.x, R1.x) L[ 5*KOPT] = v; STEP(C1.y, R1.y)     \
    L[ 6*KOPT] = v; STEP(C1.z, R1.z) L[ 7*KOPT] = v; STEP(C1.w, R1.w)     \
    L[ 8*KOPT] = v; STEP(C2.x, R2.x) L[ 9*KOPT] = v; STEP(C2.y, R2.y)     \
    L[10*KOPT] = v; STEP(C2.z, R2.z) L[11*KOPT] = v; STEP(C2.w, R2.w)     \
    L[12*KOPT] = v; STEP(C3.x, R3.x) L[13*KOPT] = v; STEP(C3.y, R3.y)     \
    L[14*KOPT] = v; STEP(C3.z, R3.z) L[15*KOPT] = v; STEP(C3.w, R3.w)

// Wave-local LDS fence: order + drain this wave's ds ops (no block barrier).
#define WAVE_LGKM0()                                        \
    do {                                                    \
        __builtin_amdgcn_wave_barrier();                    \
        asm volatile("s_waitcnt lgkmcnt(0)" ::: "memory");  \
        __builtin_amdgcn_wave_barrier();                    \
    } while (0)

// ---------------------------------------------------------------------------
// Barrier-free wave-autonomous fused kernel.
// Wave = 4 rows x 16 option-lanes (k>=10 idle: their v never updates, LDS
// writes diverted to a dump region). Each wave stages its own 4x16-trial tile
// of emitted values in its own LDS slice, waits lgkmcnt(0) (wave-local, ~30cy),
// then fires coalesced float4 stores that are NEVER drained. No __syncthreads
// anywhere -> no vmcnt(0) block-wide drains; 8 independent waves/CU overlap
// each other's load/store latency.
// ---------------------------------------------------------------------------
__global__ __launch_bounds__(BLOCK) void rw_wave(
    const int* __restrict__ choices, const float* __restrict__ rewards,
    const float* __restrict__ apP, const float* __restrict__ amP,
    const float* __restrict__ ivP, float* __restrict__ out, int N)
{
    __shared__ float lds0[BUFSZ];    // tile-A buffer (even tiles)
    __shared__ float lds1[BUFSZ];    // tile-B buffer (odd tiles)
    __shared__ float dump[256];      // sink for idle-lane LDS writes

    const int j    = threadIdx.x;
    const int lane = j & 63;
    const int wid  = j >> 6;
    const int urow = (wid << 2) + (lane >> 4);   // block-local row 0..15
    const int k    = lane & (KPAD - 1);          // 0..15; active when <10
    const bool act = (k < KOPT);

    int row = blockIdx.x * RPB + urow;
    if (row >= N) row = N - 1;                   // grid exact for N=8192

    const float ap = sigmoidf_(apP[0]);
    const float am = sigmoidf_(amP[0]);
    float v = 100.0f * tanhf(ivP[0]);

    const int4*   c4 = (const int4*)  (choices + (size_t)row * T_TRIALS);
    const float4* r4 = (const float4*)(rewards + (size_t)row * T_TRIALS);

    // Named per-buffer write bases (no runtime-indexed pointer array -> no scratch).
    float* LA = act ? &lds0[urow * LSTRIDE + k] : &dump[lane];
    float* LB = act ? &lds1[urow * LSTRIDE + k] : &dump[lane];

    // Store assignment: wave tile = 4 rows x 160 floats = 160 float4.
    // idx = lane, lane+64, lane+128(<32) -> uu = idx/40 (wave-local row), f4 = idx%40.
    int          s_uu[3], s_f4[3];
    bool         s_on[3];
    const float* s_srcA[3];
    const float* s_srcB[3];
    float*       s_dst[3];
#pragma unroll
    for (int w = 0; w < 3; ++w) {
        int idx = lane + w * 64;
        bool on = idx < RPW * TI * KOPT / 4;     // 160
        if (!on) idx = 0;
        int uu = idx / 40;
        int f4 = idx - uu * 40;
        int wrow = (wid << 2) + uu;              // block-local row
        int grow = blockIdx.x * RPB + wrow;
        if (grow >= N) { on = false; grow = N - 1; }
        s_uu[w] = uu; s_f4[w] = f4; s_on[w] = on;
        s_srcA[w] = &lds0[wrow * LSTRIDE + f4 * 4];
        s_srcB[w] = &lds1[wrow * LSTRIDE + f4 * 4];
        s_dst[w]  = out + (size_t)grow * T_TRIALS * KOPT + (size_t)f4 * 4;
    }

    // Preload tiles 0 (A regs) and 1 (B regs).
    int4   ca0 = c4[0], ca1 = c4[1], ca2 = c4[2], ca3 = c4[3];
    float4 ra0 = r4[0], ra1 = r4[1], ra2 = r4[2], ra3 = r4[3];
    int4   cb0 = c4[4], cb1 = c4[5], cb2 = c4[6], cb3 = c4[7];
    float4 rb0 = r4[4], rb1 = r4[5], rb2 = r4[6], rb3 = r4[7];

    for (int t2 = 0; t2 < NTILES; t2 += 2) {
        // ---------------- tile A = t2 (buffer lds0) ----------------
        EMIT16(LA, ca0, ca1, ca2, ca3, ra0, ra1, ra2, ra3)
        {   // prefetch tile t2+2 into A regs (wraps harmlessly at the end)
            int nx = ((t2 + 2) & (NTILES - 1)) * 4;
            ca0 = c4[nx]; ca1 = c4[nx+1]; ca2 = c4[nx+2]; ca3 = c4[nx+3];
            ra0 = r4[nx]; ra1 = r4[nx+1]; ra2 = r4[nx+2]; ra3 = r4[nx+3];
        }
        WAVE_LGKM0();
#pragma unroll
        for (int w = 0; w < 3; ++w)
            if (s_on[w]) {
                float4 val = *(const float4*)s_srcA[w];
                *(float4*)(s_dst[w]) = val;
            }

        // ---------------- tile B = t2+1 (buffer lds1) ----------------
        EMIT16(LB, cb0, cb1, cb2, cb3, rb0, rb1, rb2, rb3)
        {   // prefetch tile t2+3 into B regs
            int nx = ((t2 + 3) & (NTILES - 1)) * 4;
            cb0 = c4[nx]; cb1 = c4[nx+1]; cb2 = c4[nx+2]; cb3 = c4[nx+3];
            rb0 = r4[nx]; rb1 = r4[nx+1]; rb2 = r4[nx+2]; rb3 = r4[nx+3];
        }
        WAVE_LGKM0();
#pragma unroll
        for (int w = 0; w < 3; ++w)
            if (s_on[w]) {
                float4 val = *(const float4*)s_srcB[w];
                *(float4*)(s_dst[w] + TI * KOPT) = val;
            }

#pragma unroll
        for (int w = 0; w < 3; ++w)
            s_dst[w] += 2 * TI * KOPT;           // advance 320 floats / iter
    }
}

extern "C" void kernel_launch(void* const* d_in, const int* in_sizes, int n_in,
                              void* d_out, int out_size, void* d_ws, size_t ws_size,
                              hipStream_t stream)
{
    const int*   choices = (const int*)  d_in[0];
    const float* rewards = (const float*)d_in[1];
    const float* ap      = (const float*)d_in[2];
    const float* am      = (const float*)d_in[3];
    const float* iv      = (const float*)d_in[4];
    float* out = (float*)d_out;

    int N    = in_sizes[0] / T_TRIALS;          // 8192
    int grid = (N + RPB - 1) / RPB;             // 512 blocks -> 2 per CU, 8 waves/CU

    rw_wave<<<grid, BLOCK, 0, stream>>>(choices, rewards, ap, am, iv, out, N);
}

// Round 3
// 439.746 us; speedup vs baseline: 1.0865x; 1.0170x over previous
//
#include <hip/hip_runtime.h>
#include <math.h>

// Problem constants: N=8192 rows, T=1024 trials, K=10 options
#define T_TRIALS 1024
#define KOPT     10
#define RPB      32                  // rows per block
#define TI       16                  // trials per LDS tile
#define NTILES   (T_TRIALS / TI)     // 64
#define LSTRIDE  164                 // 16*10 + 4 pad floats (16B-aligned, rotates banks)
#define BLOCK    (RPB * KOPT)        // 320 threads = 5 waves

__device__ __forceinline__ float sigmoidf_(float x) { return 1.0f / (1.0f + expf(-x)); }

// One RW update for the option-k chain (branchless; bit-exact vs reference:
// NaN reward => ref computes chosen + ap*0 == chosen exactly == "no update",
// so the NaN test folds into the update predicate, off the dependent chain).
#define STEP(ct, rt)                                              \
    {                                                             \
        bool  upd = ((ct) == k) && ((rt) == (rt));                \
        float pe  = (rt) - v;                                     \
        float lr  = (pe >= 0.0f) ? ap : am;                       \
        float vn  = fmaf(lr, pe, v);                              \
        v = upd ? vn : v;                                         \
    }

// Fused single-pass kernel: thread (u,k) owns row blockIdx*32+u, option k, and
// scans all 1024 trials keeping v in a register. Emitted values (pre-update)
// are staged in double-buffered LDS tiles of 16 trials x 10 options per row,
// then the whole block streams each tile to global as coalesced float4.
//
// Roofline note (round-2 conclusion): mandatory traffic = 335.5 MB out +
// 67.1 MB in = 402.7 MB; at the ~6.2 TB/s this box sustains on the poison
// fill that is ~65 us. This dispatch measures <212 us-absent-from-top-5 and
// behaves BW-bound (4x occupancy and barrier removal both null) => at roofline.
__global__ __launch_bounds__(BLOCK) void rw_fused(
    const int* __restrict__ choices, const float* __restrict__ rewards,
    const float* __restrict__ apP, const float* __restrict__ amP,
    const float* __restrict__ ivP, float* __restrict__ out, int N)
{
    __shared__ float lds[2][RPB * LSTRIDE];   // 2 * 32 * 164 * 4 = 41984 B

    const int j   = threadIdx.x;
    const int u   = j / KOPT;                 // local row 0..31
    const int k   = j - u * KOPT;             // option 0..9
    int row = blockIdx.x * RPB + u;
    if (row >= N) row = N - 1;                // safety clamp (grid is exact for N=8192)

    const float ap = sigmoidf_(apP[0]);
    const float am = sigmoidf_(amP[0]);
    float v = 100.0f * tanhf(ivP[0]);

    const int4*   c4 = (const int4*)  (choices + (size_t)row * T_TRIALS);
    const float4* r4 = (const float4*)(rewards + (size_t)row * T_TRIALS);

    // Per-thread LDS write bases for the two buffers.
    float* Lw[2] = { &lds[0][u * LSTRIDE + k], &lds[1][u * LSTRIDE + k] };

    // Store-loop assignment (fixed per thread): 4 float4 per tile.
    // idx = w*320 + j -> local row uu = idx/40, vector f4 = idx%40.
    int    s_uu[4], s_f4[4];
    float* s_dst[4];
    bool   s_ok[4];
#pragma unroll
    for (int w = 0; w < 4; ++w) {
        int idx = w * BLOCK + j;
        int uu  = idx / 40;
        int f4  = idx - uu * 40;
        s_uu[w] = uu; s_f4[w] = f4;
        int grow = blockIdx.x * RPB + uu;
        s_ok[w]  = grow < N;
        if (grow >= N) grow = N - 1;
        s_dst[w] = out + (size_t)grow * T_TRIALS * KOPT + (size_t)f4 * 4;
    }

    // Prefetch tile 0.
    int4   ca0 = c4[0], ca1 = c4[1], ca2 = c4[2], ca3 = c4[3];
    float4 ra0 = r4[0], ra1 = r4[1], ra2 = r4[2], ra3 = r4[3];

    for (int tile = 0; tile < NTILES; ++tile) {
        // Prefetch next tile (wraps on the last iteration; values unused then).
        int nx = ((tile + 1) & (NTILES - 1)) * 4;
        int4   cb0 = c4[nx + 0], cb1 = c4[nx + 1], cb2 = c4[nx + 2], cb3 = c4[nx + 3];
        float4 rb0 = r4[nx + 0], rb1 = r4[nx + 1], rb2 = r4[nx + 2], rb3 = r4[nx + 3];

        // Emit (pre-update) + update, 16 trials into LDS buffer tile&1.
        float* L = Lw[tile & 1];
        L[ 0*KOPT] = v; STEP(ca0.x, ra0.x) L[ 1*KOPT] = v; STEP(ca0.y, ra0.y)
        L[ 2*KOPT] = v; STEP(ca0.z, ra0.z) L[ 3*KOPT] = v; STEP(ca0.w, ra0.w)
        L[ 4*KOPT] = v; STEP(ca1.x, ra1.x) L[ 5*KOPT] = v; STEP(ca1.y, ra1.y)
        L[ 6*KOPT] = v; STEP(ca1.z, ra1.z) L[ 7*KOPT] = v; STEP(ca1.w, ra1.w)
        L[ 8*KOPT] = v; STEP(ca2.x, ra2.x) L[ 9*KOPT] = v; STEP(ca2.y, ra2.y)
        L[10*KOPT] = v; STEP(ca2.z, ra2.z) L[11*KOPT] = v; STEP(ca2.w, ra2.w)
        L[12*KOPT] = v; STEP(ca3.x, ra3.x) L[13*KOPT] = v; STEP(ca3.y, ra3.y)
        L[14*KOPT] = v; STEP(ca3.z, ra3.z) L[15*KOPT] = v; STEP(ca3.w, ra3.w)

        __syncthreads();   // writes of buf (tile&1) visible; also fences the
                           // buf reuse hazard one iteration later (WAR covered
                           // because reads below complete before this barrier
                           // on the NEXT iteration's opposite buffer).

        // Cooperative coalesced store of this tile: 32 rows x 160 floats.
        const float* Ls = &lds[tile & 1][0];
#pragma unroll
        for (int w = 0; w < 4; ++w) {
            float4 val = *(const float4*)(Ls + s_uu[w] * LSTRIDE + s_f4[w] * 4);
            if (s_ok[w]) *(float4*)s_dst[w] = val;
            s_dst[w] += TI * KOPT;          // advance 160 floats to next tile
        }

        ca0 = cb0; ca1 = cb1; ca2 = cb2; ca3 = cb3;
        ra0 = rb0; ra1 = rb1; ra2 = rb2; ra3 = rb3;
    }
}

extern "C" void kernel_launch(void* const* d_in, const int* in_sizes, int n_in,
                              void* d_out, int out_size, void* d_ws, size_t ws_size,
                              hipStream_t stream)
{
    const int*   choices = (const int*)  d_in[0];
    const float* rewards = (const float*)d_in[1];
    const float* ap      = (const float*)d_in[2];
    const float* am      = (const float*)d_in[3];
    const float* iv      = (const float*)d_in[4];
    float* out = (float*)d_out;

    int N    = in_sizes[0] / T_TRIALS;        // 8192
    int grid = (N + RPB - 1) / RPB;           // 256 blocks -> 1 per CU

    rw_fused<<<grid, BLOCK, 0, stream>>>(choices, rewards, ap, am, iv, out, N);
}